// Round 1
// baseline (476.918 us; speedup 1.0000x reference)
//
#include <hip/hip_runtime.h>
#include <stdint.h>

typedef unsigned short u16;
typedef u16   us8 __attribute__((ext_vector_type(8)));
typedef __bf16 bf8 __attribute__((ext_vector_type(8)));
typedef float f4  __attribute__((ext_vector_type(4)));

__device__ __forceinline__ u16 f2bf(float f) {
    uint32_t u = __builtin_bit_cast(uint32_t, f);
    uint32_t r = (u + 0x7fffu + ((u >> 16) & 1u)) >> 16;   // RNE
    return (u16)r;
}
__device__ __forceinline__ float bf2f(u16 s) {
    uint32_t u = ((uint32_t)s) << 16;
    return __builtin_bit_cast(float, u);
}
__device__ __forceinline__ f4 mfma16(bf8 a, bf8 b, f4 c) {
    return __builtin_amdgcn_mfma_f32_16x16x32_bf16(a, b, c, 0, 0, 0);
}

// ---------------------------------------------------------------------------
// Kernel 1: fused theta/phi/g projection GEMM.
// P[n][384][4096] (bf16) = Wall[384][512] * X[n][512][4096]
// Tile: BM=64, BN=128, BK=32; 4 waves, each 32x64 (2x4 acc tiles of 16x16).
// ---------------------------------------------------------------------------
__global__ __launch_bounds__(256) void proj_gemm(
    const float* __restrict__ w_theta, const float* __restrict__ w_phi,
    const float* __restrict__ w_g, const float* __restrict__ x,
    u16* __restrict__ P)
{
    const int nt = blockIdx.x;          // 0..31  (s tiles of 128)
    const int mt = blockIdx.y;          // 0..5   (out-channel tiles of 64)
    const int nb = blockIdx.z;          // batch
    const int tid = threadIdx.x;
    const int wave = tid >> 6, lane = tid & 63;
    const int quad = lane >> 4, l15 = lane & 15;
    const int wm = (wave >> 1) * 32, wn = (wave & 1) * 64;
    const int s0 = nt * 128;

    const float* A; int m_off;
    if (mt == 0)      { A = w_theta; m_off = 0; }
    else if (mt == 1) { A = w_phi;   m_off = 0; }
    else              { A = w_g;     m_off = (mt - 2) * 64; }

    const float* Bx = x + (size_t)nb * 512 * 4096;

    __shared__ u16 a_lds[64 * 40];      // [m][k], row stride 40 (pad 8)
    __shared__ u16 b_lds[128 * 40];     // [ncol][k] (transposed), stride 40

    f4 acc[2][4];
    f4 z = {0.f, 0.f, 0.f, 0.f};
    for (int i = 0; i < 2; i++) for (int j = 0; j < 4; j++) acc[i][j] = z;

    for (int k0 = 0; k0 < 512; k0 += 32) {
        // stage A tile 64x32 (fp32 -> bf16)
        {
            int m = tid >> 2, kq = (tid & 3) * 8;
            const float* src = A + (size_t)(m_off + m) * 512 + k0 + kq;
            float4 f0 = *(const float4*)(src);
            float4 f1 = *(const float4*)(src + 4);
            us8 v;
            v[0]=f2bf(f0.x); v[1]=f2bf(f0.y); v[2]=f2bf(f0.z); v[3]=f2bf(f0.w);
            v[4]=f2bf(f1.x); v[5]=f2bf(f1.y); v[6]=f2bf(f1.z); v[7]=f2bf(f1.w);
            *(us8*)&a_lds[m * 40 + kq] = v;
        }
        // stage B tile 32x128, transposed into [ncol][k]
        {
            int k = tid >> 3, c0 = (tid & 7) * 16;
            const float* src = Bx + (size_t)(k0 + k) * 4096 + s0 + c0;
            for (int jj = 0; jj < 4; jj++) {
                float4 f = *(const float4*)(src + jj * 4);
                int c = c0 + jj * 4;
                b_lds[(c + 0) * 40 + k] = f2bf(f.x);
                b_lds[(c + 1) * 40 + k] = f2bf(f.y);
                b_lds[(c + 2) * 40 + k] = f2bf(f.z);
                b_lds[(c + 3) * 40 + k] = f2bf(f.w);
            }
        }
        __syncthreads();
        bf8 af[2], bfr[4];
        for (int i = 0; i < 2; i++)
            af[i] = __builtin_bit_cast(bf8, *(const us8*)&a_lds[(wm + i*16 + l15)*40 + quad*8]);
        for (int j = 0; j < 4; j++)
            bfr[j] = __builtin_bit_cast(bf8, *(const us8*)&b_lds[(wn + j*16 + l15)*40 + quad*8]);
        for (int i = 0; i < 2; i++)
            for (int j = 0; j < 4; j++)
                acc[i][j] = mfma16(af[i], bfr[j], acc[i][j]);
        __syncthreads();
    }
    // epilogue: D[row=quad*4+r][col=l15]  -> P bf16
    for (int i = 0; i < 2; i++) {
        int row = mt * 64 + wm + i * 16 + quad * 4;
        for (int j = 0; j < 4; j++) {
            int col = s0 + wn + j * 16 + l15;
            for (int rr = 0; rr < 4; rr++)
                P[((size_t)nb * 384 + row + rr) * 4096 + col] = f2bf(acc[i][j][rr]);
        }
    }
}

// ---------------------------------------------------------------------------
// Kernel 2: theta transpose  P[n][0:64][s] -> thetaT[n][s][64]
// ---------------------------------------------------------------------------
__global__ __launch_bounds__(256) void theta_trans(
    const u16* __restrict__ P, u16* __restrict__ thetaT)
{
    int n = blockIdx.y, s0 = blockIdx.x * 64;
    int tid = threadIdx.x;
    int s_loc = tid & 63, d0 = (tid >> 6) * 16;
    const u16* base = P + (size_t)n * 384 * 4096 + s0 + s_loc;
    us8 v0, v1;
    for (int i = 0; i < 8; i++) v0[i] = base[(size_t)(d0 + i) * 4096];
    for (int i = 0; i < 8; i++) v1[i] = base[(size_t)(d0 + 8 + i) * 4096];
    u16* dst = thetaT + ((size_t)n * 4096 + s0 + s_loc) * 64 + d0;
    *(us8*)dst = v0;
    *(us8*)(dst + 8) = v1;
}

// ---------------------------------------------------------------------------
// Kernel 3: phi pool+transpose  P[n][64:128][s] --2x2 maxpool--> phiT[n][t][64]
// ---------------------------------------------------------------------------
__global__ __launch_bounds__(256) void phi_pool(
    const u16* __restrict__ P, u16* __restrict__ phiT)
{
    int n = blockIdx.y, t0 = blockIdx.x * 64;
    int tid = threadIdx.x;
    int t_loc = tid & 63, d0 = (tid >> 6) * 16;
    int t = t0 + t_loc;
    int h2 = t >> 5, w2 = t & 31;
    size_t s00 = (size_t)h2 * 128 + w2 * 2;
    const u16* base = P + ((size_t)n * 384 + 64) * 4096 + s00;
    us8 v0, v1;
    for (int i = 0; i < 16; i++) {
        const u16* r = base + (size_t)(d0 + i) * 4096;
        float m = fmaxf(fmaxf(bf2f(r[0]), bf2f(r[1])),
                        fmaxf(bf2f(r[64]), bf2f(r[65])));
        u16 us = f2bf(m);       // exact: m is already a bf16 value
        if (i < 8) v0[i] = us; else v1[i - 8] = us;
    }
    u16* dst = phiT + ((size_t)n * 1024 + t) * 64 + d0;
    *(us8*)dst = v0;
    *(us8*)(dst + 8) = v1;
}

// ---------------------------------------------------------------------------
// Kernel 4: g pool  P[n][128:384][s] --2x2 maxpool--> gP[n][256][1024]
// ---------------------------------------------------------------------------
__global__ __launch_bounds__(256) void g_pool(
    const u16* __restrict__ P, u16* __restrict__ gP)
{
    int n = blockIdx.y, d2 = blockIdx.x;
    int tid = threadIdx.x;
    const u16* base = P + ((size_t)n * 384 + 128 + d2) * 4096;
    u16* dst = gP + ((size_t)n * 256 + d2) * 1024;
    for (int p = 0; p < 4; p++) {
        int t = p * 256 + tid;
        int h2 = t >> 5, w2 = t & 31;
        size_t s00 = (size_t)h2 * 128 + w2 * 2;
        float m = fmaxf(fmaxf(bf2f(base[s00]), bf2f(base[s00 + 1])),
                        fmaxf(bf2f(base[s00 + 64]), bf2f(base[s00 + 65])));
        dst[t] = f2bf(m);
    }
}

// ---------------------------------------------------------------------------
// Kernel 5: attention. Per block: 64 queries (16/wave), full T=1024.
// Single pass: scores std ~2, |score|<~14 -> exp() safe without max-subtract.
// S = theta_q . phi^T (K=64), P=exp(S), O += P.G' (K=32 chunks), l += rowsum.
// P goes C-layout -> LDS -> A-layout (m120 pattern). Output yT[n][s][256] bf16.
// ---------------------------------------------------------------------------
__global__ __launch_bounds__(256) void attn_kernel(
    const u16* __restrict__ thetaT, const u16* __restrict__ phiT,
    const u16* __restrict__ gP, u16* __restrict__ yT)
{
    int n = blockIdx.y;
    int tid = threadIdx.x;
    int wave = tid >> 6, lane = tid & 63, quad = lane >> 4, l15 = lane & 15;
    int q0 = blockIdx.x * 64 + wave * 16;

    __shared__ u16 phi_lds[32 * 72];     // [t_loc][d], stride 72
    __shared__ u16 g_lds[256 * 40];      // [d2][t_loc], stride 40
    __shared__ u16 p_lds[4][16 * 40];    // per-wave [q_loc][t_loc], stride 40

    // theta A fragments (K=64 -> 2 frags), direct from global
    const u16* th = thetaT + ((size_t)n * 4096 + q0 + l15) * 64 + quad * 8;
    bf8 a0 = __builtin_bit_cast(bf8, *(const us8*)(th));
    bf8 a1 = __builtin_bit_cast(bf8, *(const us8*)(th + 32));

    f4 z = {0.f, 0.f, 0.f, 0.f};
    f4 acc[16];
    for (int b = 0; b < 16; b++) acc[b] = z;
    float lsum[4] = {0.f, 0.f, 0.f, 0.f};

    for (int tc = 0; tc < 1024; tc += 32) {
        // stage phi chunk [32][64]
        {
            int t_loc = tid >> 3, d0 = (tid & 7) * 8;
            *(us8*)&phi_lds[t_loc * 72 + d0] =
                *(const us8*)(phiT + ((size_t)n * 1024 + tc + t_loc) * 64 + d0);
        }
        // stage g chunk [256][32]
        {
            const u16* src = gP + ((size_t)n * 256 + tid) * 1024 + tc;
            *(us8*)&g_lds[tid * 40 + 0]  = *(const us8*)(src);
            *(us8*)&g_lds[tid * 40 + 8]  = *(const us8*)(src + 8);
            *(us8*)&g_lds[tid * 40 + 16] = *(const us8*)(src + 16);
            *(us8*)&g_lds[tid * 40 + 24] = *(const us8*)(src + 24);
        }
        __syncthreads();

        // two 16-wide S tiles -> exp -> p_lds
        for (int tt = 0; tt < 32; tt += 16) {
            bf8 b0 = __builtin_bit_cast(bf8, *(const us8*)&phi_lds[(tt + l15) * 72 + quad * 8]);
            bf8 b1 = __builtin_bit_cast(bf8, *(const us8*)&phi_lds[(tt + l15) * 72 + 32 + quad * 8]);
            f4 s = mfma16(a0, b0, z);
            s = mfma16(a1, b1, s);
            for (int rr = 0; rr < 4; rr++) {
                float p = __expf(s[rr]);
                lsum[rr] += p;
                p_lds[wave][(quad * 4 + rr) * 40 + tt + l15] = f2bf(p);
            }
        }
        // P back as A fragment (k = 32 local t)
        bf8 ap = __builtin_bit_cast(bf8, *(const us8*)&p_lds[wave][l15 * 40 + quad * 8]);
        // PV over 16 d2-blocks
        for (int b = 0; b < 16; b++) {
            bf8 bg = __builtin_bit_cast(bf8, *(const us8*)&g_lds[(b * 16 + l15) * 40 + quad * 8]);
            acc[b] = mfma16(ap, bg, acc[b]);
        }
        __syncthreads();
    }

    // softmax denominator: reduce across the 16 lanes of each quad
    for (int rr = 0; rr < 4; rr++) {
        float v = lsum[rr];
        v += __shfl_xor(v, 1);
        v += __shfl_xor(v, 2);
        v += __shfl_xor(v, 4);
        v += __shfl_xor(v, 8);
        lsum[rr] = 1.0f / v;
    }
    for (int b = 0; b < 16; b++)
        for (int rr = 0; rr < 4; rr++) {
            size_t row = (size_t)n * 4096 + q0 + quad * 4 + rr;
            yT[row * 256 + b * 16 + l15] = f2bf(acc[b][rr] * lsum[rr]);
        }
}

// ---------------------------------------------------------------------------
// Kernel 6: o-projection + residual.
// out[n][c][s] = gamma * (w_o[c][:] . yT[n][s][:]) + x[n][c][s]
// Same tile structure as proj_gemm; B (yT) is [N][K] bf16 -> direct-copy stage.
// ---------------------------------------------------------------------------
__global__ __launch_bounds__(256) void oproj_gemm(
    const float* __restrict__ w_o, const u16* __restrict__ yT,
    const float* __restrict__ x, const float* __restrict__ gamma,
    float* __restrict__ out)
{
    const int nt = blockIdx.x;          // 0..31 (s tiles)
    const int mt = blockIdx.y;          // 0..7  (c tiles)
    const int nb = blockIdx.z;
    const int tid = threadIdx.x;
    const int wave = tid >> 6, lane = tid & 63;
    const int quad = lane >> 4, l15 = lane & 15;
    const int wm = (wave >> 1) * 32, wn = (wave & 1) * 64;
    const int s0 = nt * 128;

    __shared__ u16 a_lds[64 * 40];
    __shared__ u16 b_lds[128 * 40];

    f4 acc[2][4];
    f4 z = {0.f, 0.f, 0.f, 0.f};
    for (int i = 0; i < 2; i++) for (int j = 0; j < 4; j++) acc[i][j] = z;

    for (int k0 = 0; k0 < 256; k0 += 32) {
        {
            int m = tid >> 2, kq = (tid & 3) * 8;
            const float* src = w_o + (size_t)(mt * 64 + m) * 256 + k0 + kq;
            float4 f0 = *(const float4*)(src);
            float4 f1 = *(const float4*)(src + 4);
            us8 v;
            v[0]=f2bf(f0.x); v[1]=f2bf(f0.y); v[2]=f2bf(f0.z); v[3]=f2bf(f0.w);
            v[4]=f2bf(f1.x); v[5]=f2bf(f1.y); v[6]=f2bf(f1.z); v[7]=f2bf(f1.w);
            *(us8*)&a_lds[m * 40 + kq] = v;
        }
        {
            int s_loc = tid >> 1, kq = (tid & 1) * 16;
            const u16* src = yT + ((size_t)nb * 4096 + s0 + s_loc) * 256 + k0 + kq;
            *(us8*)&b_lds[s_loc * 40 + kq]     = *(const us8*)(src);
            *(us8*)&b_lds[s_loc * 40 + kq + 8] = *(const us8*)(src + 8);
        }
        __syncthreads();
        bf8 af[2], bfr[4];
        for (int i = 0; i < 2; i++)
            af[i] = __builtin_bit_cast(bf8, *(const us8*)&a_lds[(wm + i*16 + l15)*40 + quad*8]);
        for (int j = 0; j < 4; j++)
            bfr[j] = __builtin_bit_cast(bf8, *(const us8*)&b_lds[(wn + j*16 + l15)*40 + quad*8]);
        for (int i = 0; i < 2; i++)
            for (int j = 0; j < 4; j++)
                acc[i][j] = mfma16(af[i], bfr[j], acc[i][j]);
        __syncthreads();
    }
    float g0 = gamma[0];
    for (int i = 0; i < 2; i++) {
        int c = mt * 64 + wm + i * 16 + quad * 4;
        for (int j = 0; j < 4; j++) {
            int s = s0 + wn + j * 16 + l15;
            for (int rr = 0; rr < 4; rr++) {
                size_t idx = ((size_t)nb * 512 + c + rr) * 4096 + s;
                out[idx] = g0 * acc[i][j][rr] + x[idx];
            }
        }
    }
}

// ---------------------------------------------------------------------------
// Workspace layout (bytes, all 256-aligned). Total ~103 MB.
//   P      : [16][384][4096] bf16   @ 0          (50,331,648)
//   thetaT : [16][4096][64]  bf16   @ 50331648   ( 8,388,608)
//   phiT   : [16][1024][64]  bf16   @ 58720256   ( 2,097,152)
//   gP     : [16][256][1024] bf16   @ 60817408   ( 8,388,608)
//   yT     : [16][4096][256] bf16   @ 69205760   (33,554,432)
// ---------------------------------------------------------------------------
extern "C" void kernel_launch(void* const* d_in, const int* in_sizes, int n_in,
                              void* d_out, int out_size, void* d_ws, size_t ws_size,
                              hipStream_t stream)
{
    (void)in_sizes; (void)n_in; (void)out_size; (void)ws_size;
    const float* x       = (const float*)d_in[0];
    const float* w_theta = (const float*)d_in[1];
    const float* w_phi   = (const float*)d_in[2];
    const float* w_g     = (const float*)d_in[3];
    const float* w_o     = (const float*)d_in[4];
    const float* gamma   = (const float*)d_in[5];
    float* out = (float*)d_out;

    char* ws = (char*)d_ws;
    u16* P      = (u16*)(ws);
    u16* thetaT = (u16*)(ws + 50331648);
    u16* phiT   = (u16*)(ws + 58720256);
    u16* gP     = (u16*)(ws + 60817408);
    u16* yT     = (u16*)(ws + 69205760);

    proj_gemm  <<<dim3(32, 6, 16),  256, 0, stream>>>(w_theta, w_phi, w_g, x, P);
    theta_trans<<<dim3(64, 16),     256, 0, stream>>>(P, thetaT);
    phi_pool   <<<dim3(16, 16),     256, 0, stream>>>(P, phiT);
    g_pool     <<<dim3(256, 16),    256, 0, stream>>>(P, gP);
    attn_kernel<<<dim3(64, 16),     256, 0, stream>>>(thetaT, phiT, gP, yT);
    oproj_gemm <<<dim3(32, 8, 16),  256, 0, stream>>>(w_o, yT, x, gamma, out);
}

// Round 2
// 453.888 us; speedup vs baseline: 1.0507x; 1.0507x over previous
//
#include <hip/hip_runtime.h>
#include <stdint.h>

typedef unsigned short u16;
typedef u16   us4 __attribute__((ext_vector_type(4)));
typedef u16   us8 __attribute__((ext_vector_type(8)));
typedef __bf16 bf8 __attribute__((ext_vector_type(8)));
typedef float f4  __attribute__((ext_vector_type(4)));

__device__ __forceinline__ u16 f2bf(float f) {
    uint32_t u = __builtin_bit_cast(uint32_t, f);
    uint32_t r = (u + 0x7fffu + ((u >> 16) & 1u)) >> 16;   // RNE
    return (u16)r;
}
__device__ __forceinline__ float bf2f(u16 s) {
    uint32_t u = ((uint32_t)s) << 16;
    return __builtin_bit_cast(float, u);
}
__device__ __forceinline__ f4 mfma16(bf8 a, bf8 b, f4 c) {
    return __builtin_amdgcn_mfma_f32_16x16x32_bf16(a, b, c, 0, 0, 0);
}
__device__ __forceinline__ u16 max4bf(u16 a, u16 b, u16 c, u16 d) {
    float m = fmaxf(fmaxf(bf2f(a), bf2f(b)), fmaxf(bf2f(c), bf2f(d)));
    return f2bf(m);   // exact: m is already a bf16 value
}

// ---------------------------------------------------------------------------
// Kernel 0a: X transpose+convert.  x[n][c][4096] fp32 -> Xt[n][s][512] bf16.
// 64x64 tiles via LDS. Phase-1 store mapping: c_loc distinct per wave ->
// bank = s*36 + c_loc/2 covers all 32 banks 2-way (free, m136).
// ---------------------------------------------------------------------------
__global__ __launch_bounds__(256) void xt_kernel(
    const float* __restrict__ x, u16* __restrict__ Xt)
{
    const int s0 = blockIdx.x * 64, c0 = blockIdx.y * 64, n = blockIdx.z;
    const int tid = threadIdx.x;
    __shared__ u16 lds[64 * 72];   // [s_loc][c_loc], stride 72

    // phase 1: read 64 B per lane of row c0+c_loc, convert, store [s][c]
    {
        int c_loc = tid & 63, s_seg = (tid >> 6) * 16;
        const float* src = x + ((size_t)n * 512 + c0 + c_loc) * 4096 + s0 + s_seg;
        for (int i4 = 0; i4 < 4; i4++) {
            float4 f = *(const float4*)(src + i4 * 4);
            int s = s_seg + i4 * 4;
            lds[(s + 0) * 72 + c_loc] = f2bf(f.x);
            lds[(s + 1) * 72 + c_loc] = f2bf(f.y);
            lds[(s + 2) * 72 + c_loc] = f2bf(f.z);
            lds[(s + 3) * 72 + c_loc] = f2bf(f.w);
        }
    }
    __syncthreads();
    // phase 2: vectorized coalesced write of Xt rows
    {
        int s_loc = tid >> 2, c_seg = (tid & 3) * 16;
        u16* dst = Xt + ((size_t)n * 4096 + s0 + s_loc) * 512 + c0 + c_seg;
        *(us8*)(dst)     = *(const us8*)&lds[s_loc * 72 + c_seg];
        *(us8*)(dst + 8) = *(const us8*)&lds[s_loc * 72 + c_seg + 8];
    }
}

// ---------------------------------------------------------------------------
// Kernel 0b: weight convert. Wall_bf[384][512] = [theta;phi;g], Wo_bf[512][256].
// ---------------------------------------------------------------------------
__global__ __launch_bounds__(256) void wconv_kernel(
    const float* __restrict__ w_theta, const float* __restrict__ w_phi,
    const float* __restrict__ w_g, const float* __restrict__ w_o,
    u16* __restrict__ Wall_bf, u16* __restrict__ Wo_bf)
{
    int base = (blockIdx.x * 256 + threadIdx.x) * 4;   // 327680 total elems
    const float* src; u16* dst;
    if (base < 32768)       { src = w_theta + base;          dst = Wall_bf + base; }
    else if (base < 65536)  { src = w_phi + (base - 32768);  dst = Wall_bf + base; }
    else if (base < 196608) { src = w_g + (base - 65536);    dst = Wall_bf + base; }
    else                    { src = w_o + (base - 196608);   dst = Wo_bf + (base - 196608); }
    float4 f = *(const float4*)src;
    us4 v; v[0] = f2bf(f.x); v[1] = f2bf(f.y); v[2] = f2bf(f.z); v[3] = f2bf(f.w);
    *(us4*)dst = v;
}

// ---------------------------------------------------------------------------
// Kernel 1: projection GEMM (transposed output).
// PT[n][s][384] = Xt[n][s][:512] . Wall_bf[row][:512]^T
// Tile BM=128 (s) x BN=128 (row) x BK=32; 4 waves, each 64x64 (4x4 acc).
// All staging = pure us8 copies (no convert/transpose in K-loop).
// ---------------------------------------------------------------------------
__global__ __launch_bounds__(256) void projT_gemm(
    const u16* __restrict__ Xt, const u16* __restrict__ Wall_bf,
    u16* __restrict__ PT)
{
    const int s0 = blockIdx.x * 128;     // 32 tiles
    const int r0 = blockIdx.y * 128;     // 3 tiles (384 rows)
    const int nb = blockIdx.z;
    const int tid = threadIdx.x;
    const int wave = tid >> 6, lane = tid & 63;
    const int quad = lane >> 4, l15 = lane & 15;
    const int wm = (wave >> 1) * 64, wn = (wave & 1) * 64;

    __shared__ u16 a_lds[128 * 40];   // [s_loc][k], stride 40
    __shared__ u16 b_lds[128 * 40];   // [row_loc][k], stride 40

    f4 acc[4][4];
    f4 z = {0.f, 0.f, 0.f, 0.f};
    for (int i = 0; i < 4; i++) for (int j = 0; j < 4; j++) acc[i][j] = z;

    const u16* Abase = Xt + ((size_t)nb * 4096 + s0) * 512;
    const int m = tid >> 1, kseg = (tid & 1) * 16;

    for (int k0 = 0; k0 < 512; k0 += 32) {
        *(us8*)&a_lds[m * 40 + kseg]     = *(const us8*)(Abase + (size_t)m * 512 + k0 + kseg);
        *(us8*)&a_lds[m * 40 + kseg + 8] = *(const us8*)(Abase + (size_t)m * 512 + k0 + kseg + 8);
        *(us8*)&b_lds[m * 40 + kseg]     = *(const us8*)(Wall_bf + (size_t)(r0 + m) * 512 + k0 + kseg);
        *(us8*)&b_lds[m * 40 + kseg + 8] = *(const us8*)(Wall_bf + (size_t)(r0 + m) * 512 + k0 + kseg + 8);
        __syncthreads();
        bf8 af[4], bfr[4];
        for (int i = 0; i < 4; i++)
            af[i]  = __builtin_bit_cast(bf8, *(const us8*)&a_lds[(wm + i*16 + l15)*40 + quad*8]);
        for (int j = 0; j < 4; j++)
            bfr[j] = __builtin_bit_cast(bf8, *(const us8*)&b_lds[(wn + j*16 + l15)*40 + quad*8]);
        for (int i = 0; i < 4; i++)
            for (int j = 0; j < 4; j++)
                acc[i][j] = mfma16(af[i], bfr[j], acc[i][j]);
        __syncthreads();
    }
    // D: m(s) = quad*4+rr per i-tile, n(row) = l15 per j-tile
    for (int i = 0; i < 4; i++) {
        int s_idx = s0 + wm + i * 16 + quad * 4;
        for (int rr = 0; rr < 4; rr++) {
            u16* dst = PT + ((size_t)nb * 4096 + s_idx + rr) * 384 + r0 + wn + l15;
            for (int j = 0; j < 4; j++)
                dst[j * 16] = f2bf(acc[i][j][rr]);
        }
    }
}

// ---------------------------------------------------------------------------
// Kernel 3: phi pool.  PT[n][s][64:128] --2x2 maxpool over s--> phiT[n][t][64]
// ---------------------------------------------------------------------------
__global__ __launch_bounds__(256) void phi_pool2(
    const u16* __restrict__ PT, u16* __restrict__ phiT)
{
    int n = blockIdx.y, t0 = blockIdx.x * 64;
    int tid = threadIdx.x;
    int t_loc = tid >> 2, d0 = (tid & 3) * 16;
    int t = t0 + t_loc;
    int h2 = t >> 5, w2 = t & 31;
    int s00 = h2 * 128 + w2 * 2;
    const u16* base = PT + ((size_t)n * 4096) * 384 + 64 + d0;
    us8 r[4][2];
    int soff[4] = {s00, s00 + 1, s00 + 64, s00 + 65};
    for (int p = 0; p < 4; p++) {
        r[p][0] = *(const us8*)(base + (size_t)soff[p] * 384);
        r[p][1] = *(const us8*)(base + (size_t)soff[p] * 384 + 8);
    }
    us8 o0, o1;
    for (int i = 0; i < 8; i++) {
        o0[i] = max4bf(r[0][0][i], r[1][0][i], r[2][0][i], r[3][0][i]);
        o1[i] = max4bf(r[0][1][i], r[1][1][i], r[2][1][i], r[3][1][i]);
    }
    u16* dst = phiT + ((size_t)n * 1024 + t) * 64 + d0;
    *(us8*)dst = o0;
    *(us8*)(dst + 8) = o1;
}

// ---------------------------------------------------------------------------
// Kernel 4: g pool + transpose. PT[n][s][128:384] --pool--> gP[n][256][1024]
// 64t x 64d tiles; LDS transpose with conflict-free mappings.
// ---------------------------------------------------------------------------
__global__ __launch_bounds__(256) void g_poolT(
    const u16* __restrict__ PT, u16* __restrict__ gP)
{
    int t0 = blockIdx.x * 64, d0 = blockIdx.y * 64, n = blockIdx.z;
    int tid = threadIdx.x;
    __shared__ u16 lds[64 * 72];   // [d_loc][t_loc], stride 72

    // phase 1: pool 16 d per thread; t_loc distinct per wave -> free stores
    {
        int t_loc = tid & 63, dseg = (tid >> 6) * 16;
        int t = t0 + t_loc;
        int h2 = t >> 5, w2 = t & 31;
        int s00 = h2 * 128 + w2 * 2;
        const u16* base = PT + ((size_t)n * 4096) * 384 + 128 + d0 + dseg;
        us8 r[4][2];
        int soff[4] = {s00, s00 + 1, s00 + 64, s00 + 65};
        for (int p = 0; p < 4; p++) {
            r[p][0] = *(const us8*)(base + (size_t)soff[p] * 384);
            r[p][1] = *(const us8*)(base + (size_t)soff[p] * 384 + 8);
        }
        for (int i = 0; i < 8; i++) {
            lds[(dseg + i) * 72 + t_loc]     = max4bf(r[0][0][i], r[1][0][i], r[2][0][i], r[3][0][i]);
            lds[(dseg + 8 + i) * 72 + t_loc] = max4bf(r[0][1][i], r[1][1][i], r[2][1][i], r[3][1][i]);
        }
    }
    __syncthreads();
    // phase 2: vectorized write of gP rows
    {
        int d_loc = tid >> 2, t_seg = (tid & 3) * 16;
        u16* dst = gP + ((size_t)n * 256 + d0 + d_loc) * 1024 + t0 + t_seg;
        *(us8*)(dst)     = *(const us8*)&lds[d_loc * 72 + t_seg];
        *(us8*)(dst + 8) = *(const us8*)&lds[d_loc * 72 + t_seg + 8];
    }
}

// ---------------------------------------------------------------------------
// Kernel 5: attention (unchanged structure; theta read strided from PT).
// Per block: 64 queries (16/wave), full T=1024. Single pass, no max-subtract
// (|score| < ~14 -> exp safe in fp32).
// ---------------------------------------------------------------------------
__global__ __launch_bounds__(256) void attn_kernel(
    const u16* __restrict__ PT, const u16* __restrict__ phiT,
    const u16* __restrict__ gP, u16* __restrict__ yT)
{
    int n = blockIdx.y;
    int tid = threadIdx.x;
    int wave = tid >> 6, lane = tid & 63, quad = lane >> 4, l15 = lane & 15;
    int q0 = blockIdx.x * 64 + wave * 16;

    __shared__ u16 phi_lds[32 * 72];     // [t_loc][d], stride 72
    __shared__ u16 g_lds[256 * 40];      // [d2][t_loc], stride 40
    __shared__ u16 p_lds[4][16 * 40];    // per-wave [q_loc][t_loc], stride 40

    // theta A fragments (K=64 -> 2 frags); strided view of PT cols [0:64)
    const u16* th = PT + ((size_t)n * 4096 + q0 + l15) * 384 + quad * 8;
    bf8 a0 = __builtin_bit_cast(bf8, *(const us8*)(th));
    bf8 a1 = __builtin_bit_cast(bf8, *(const us8*)(th + 32));

    f4 z = {0.f, 0.f, 0.f, 0.f};
    f4 acc[16];
    for (int b = 0; b < 16; b++) acc[b] = z;
    float lsum[4] = {0.f, 0.f, 0.f, 0.f};

    for (int tc = 0; tc < 1024; tc += 32) {
        {
            int t_loc = tid >> 3, d0 = (tid & 7) * 8;
            *(us8*)&phi_lds[t_loc * 72 + d0] =
                *(const us8*)(phiT + ((size_t)n * 1024 + tc + t_loc) * 64 + d0);
        }
        {
            const u16* src = gP + ((size_t)n * 256 + tid) * 1024 + tc;
            *(us8*)&g_lds[tid * 40 + 0]  = *(const us8*)(src);
            *(us8*)&g_lds[tid * 40 + 8]  = *(const us8*)(src + 8);
            *(us8*)&g_lds[tid * 40 + 16] = *(const us8*)(src + 16);
            *(us8*)&g_lds[tid * 40 + 24] = *(const us8*)(src + 24);
        }
        __syncthreads();

        for (int tt = 0; tt < 32; tt += 16) {
            bf8 b0 = __builtin_bit_cast(bf8, *(const us8*)&phi_lds[(tt + l15) * 72 + quad * 8]);
            bf8 b1 = __builtin_bit_cast(bf8, *(const us8*)&phi_lds[(tt + l15) * 72 + 32 + quad * 8]);
            f4 s = mfma16(a0, b0, z);
            s = mfma16(a1, b1, s);
            for (int rr = 0; rr < 4; rr++) {
                float p = __expf(s[rr]);
                lsum[rr] += p;
                p_lds[wave][(quad * 4 + rr) * 40 + tt + l15] = f2bf(p);
            }
        }
        bf8 ap = __builtin_bit_cast(bf8, *(const us8*)&p_lds[wave][l15 * 40 + quad * 8]);
        for (int b = 0; b < 16; b++) {
            bf8 bg = __builtin_bit_cast(bf8, *(const us8*)&g_lds[(b * 16 + l15) * 40 + quad * 8]);
            acc[b] = mfma16(ap, bg, acc[b]);
        }
        __syncthreads();
    }

    for (int rr = 0; rr < 4; rr++) {
        float v = lsum[rr];
        v += __shfl_xor(v, 1);
        v += __shfl_xor(v, 2);
        v += __shfl_xor(v, 4);
        v += __shfl_xor(v, 8);
        lsum[rr] = 1.0f / v;
    }
    for (int b = 0; b < 16; b++)
        for (int rr = 0; rr < 4; rr++) {
            size_t row = (size_t)n * 4096 + q0 + quad * 4 + rr;
            yT[row * 256 + b * 16 + l15] = f2bf(acc[b][rr] * lsum[rr]);
        }
}

// ---------------------------------------------------------------------------
// Kernel 6: o-projection + residual (pre-converted bf16 W_o).
// out[n][c][s] = gamma * (Wo_bf[c][:] . yT[n][s][:]) + x[n][c][s]
// ---------------------------------------------------------------------------
__global__ __launch_bounds__(256) void oproj_gemm(
    const u16* __restrict__ Wo_bf, const u16* __restrict__ yT,
    const float* __restrict__ x, const float* __restrict__ gamma,
    float* __restrict__ out)
{
    const int nt = blockIdx.x;          // 0..31 (s tiles)
    const int mt = blockIdx.y;          // 0..7  (c tiles)
    const int nb = blockIdx.z;
    const int tid = threadIdx.x;
    const int wave = tid >> 6, lane = tid & 63;
    const int quad = lane >> 4, l15 = lane & 15;
    const int wm = (wave >> 1) * 32, wn = (wave & 1) * 64;
    const int s0 = nt * 128;

    __shared__ u16 a_lds[64 * 40];
    __shared__ u16 b_lds[128 * 40];

    f4 acc[2][4];
    f4 z = {0.f, 0.f, 0.f, 0.f};
    for (int i = 0; i < 2; i++) for (int j = 0; j < 4; j++) acc[i][j] = z;

    for (int k0 = 0; k0 < 256; k0 += 32) {
        {
            int m = tid >> 2, kq = (tid & 3) * 8;
            *(us8*)&a_lds[m * 40 + kq] =
                *(const us8*)(Wo_bf + (size_t)(mt * 64 + m) * 256 + k0 + kq);
        }
        {
            int s_loc = tid >> 1, kq = (tid & 1) * 16;
            const u16* src = yT + ((size_t)nb * 4096 + s0 + s_loc) * 256 + k0 + kq;
            *(us8*)&b_lds[s_loc * 40 + kq]     = *(const us8*)(src);
            *(us8*)&b_lds[s_loc * 40 + kq + 8] = *(const us8*)(src + 8);
        }
        __syncthreads();
        bf8 af[2], bfr[4];
        for (int i = 0; i < 2; i++)
            af[i] = __builtin_bit_cast(bf8, *(const us8*)&a_lds[(wm + i*16 + l15)*40 + quad*8]);
        for (int j = 0; j < 4; j++)
            bfr[j] = __builtin_bit_cast(bf8, *(const us8*)&b_lds[(wn + j*16 + l15)*40 + quad*8]);
        for (int i = 0; i < 2; i++)
            for (int j = 0; j < 4; j++)
                acc[i][j] = mfma16(af[i], bfr[j], acc[i][j]);
        __syncthreads();
    }
    float g0 = gamma[0];
    for (int i = 0; i < 2; i++) {
        int c = mt * 64 + wm + i * 16 + quad * 4;
        for (int j = 0; j < 4; j++) {
            int s = s0 + wn + j * 16 + l15;
            for (int rr = 0; rr < 4; rr++) {
                size_t idx = ((size_t)nb * 512 + c + rr) * 4096 + s;
                out[idx] = g0 * acc[i][j][rr] + x[idx];
            }
        }
    }
}

// ---------------------------------------------------------------------------
// Workspace layout (bytes). Xt region is dead after projT_gemm, so yT/phiT/gP
// overlay it. Total = 118,095,872 B (~113 MB).
//   Xt      : [16][4096][512] bf16  @ 0           (67,108,864)  -- dead after projT
//     yT    : [16][4096][256] bf16  @ 0           (33,554,432)  -- overlay
//     phiT  : [16][1024][64]  bf16  @ 33,554,432  ( 2,097,152)  -- overlay
//     gP    : [16][256][1024] bf16  @ 35,651,584  ( 8,388,608)  -- overlay
//   Wall_bf : [384][512] bf16       @ 67,108,864  (   393,216)
//   Wo_bf   : [512][256] bf16       @ 67,502,080  (   262,144)
//   PT      : [16][4096][384] bf16  @ 67,764,224  (50,331,648)
// ---------------------------------------------------------------------------
extern "C" void kernel_launch(void* const* d_in, const int* in_sizes, int n_in,
                              void* d_out, int out_size, void* d_ws, size_t ws_size,
                              hipStream_t stream)
{
    (void)in_sizes; (void)n_in; (void)out_size; (void)ws_size;
    const float* x       = (const float*)d_in[0];
    const float* w_theta = (const float*)d_in[1];
    const float* w_phi   = (const float*)d_in[2];
    const float* w_g     = (const float*)d_in[3];
    const float* w_o     = (const float*)d_in[4];
    const float* gamma   = (const float*)d_in[5];
    float* out = (float*)d_out;

    char* ws = (char*)d_ws;
    u16* Xt      = (u16*)(ws);
    u16* yT      = (u16*)(ws);                 // overlays Xt (dead by then)
    u16* phiT    = (u16*)(ws + 33554432);      // overlays Xt
    u16* gP      = (u16*)(ws + 35651584);      // overlays Xt
    u16* Wall_bf = (u16*)(ws + 67108864);
    u16* Wo_bf   = (u16*)(ws + 67502080);
    u16* PT      = (u16*)(ws + 67764224);

    xt_kernel  <<<dim3(64, 8, 16), 256, 0, stream>>>(x, Xt);
    wconv_kernel<<<320, 256, 0, stream>>>(w_theta, w_phi, w_g, w_o, Wall_bf, Wo_bf);
    projT_gemm <<<dim3(32, 3, 16), 256, 0, stream>>>(Xt, Wall_bf, PT);
    phi_pool2  <<<dim3(16, 16),    256, 0, stream>>>(PT, phiT);
    g_poolT    <<<dim3(16, 4, 16), 256, 0, stream>>>(PT, gP);
    attn_kernel<<<dim3(64, 16),    256, 0, stream>>>(PT, phiT, gP, yT);
    oproj_gemm <<<dim3(32, 8, 16), 256, 0, stream>>>(Wo_bf, yT, x, gamma, out);
}

// Round 3
// 433.810 us; speedup vs baseline: 1.0994x; 1.0463x over previous
//
#include <hip/hip_runtime.h>
#include <stdint.h>

typedef unsigned short u16;
typedef u16   us4 __attribute__((ext_vector_type(4)));
typedef u16   us8 __attribute__((ext_vector_type(8)));
typedef __bf16 bf8 __attribute__((ext_vector_type(8)));
typedef float f4  __attribute__((ext_vector_type(4)));

__device__ __forceinline__ u16 f2bf(float f) {
    uint32_t u = __builtin_bit_cast(uint32_t, f);
    uint32_t r = (u + 0x7fffu + ((u >> 16) & 1u)) >> 16;   // RNE
    return (u16)r;
}
__device__ __forceinline__ float bf2f(u16 s) {
    uint32_t u = ((uint32_t)s) << 16;
    return __builtin_bit_cast(float, u);
}
__device__ __forceinline__ f4 mfma16(bf8 a, bf8 b, f4 c) {
    return __builtin_amdgcn_mfma_f32_16x16x32_bf16(a, b, c, 0, 0, 0);
}
__device__ __forceinline__ u16 max4bf(u16 a, u16 b, u16 c, u16 d) {
    float m = fmaxf(fmaxf(bf2f(a), bf2f(b)), fmaxf(bf2f(c), bf2f(d)));
    return f2bf(m);   // exact: m is already a bf16 value
}

// ---------------------------------------------------------------------------
// Kernel 0a: X transpose+convert.  x[n][c][4096] fp32 -> Xt[n][s][512] bf16.
// ---------------------------------------------------------------------------
__global__ __launch_bounds__(256) void xt_kernel(
    const float* __restrict__ x, u16* __restrict__ Xt)
{
    const int s0 = blockIdx.x * 64, c0 = blockIdx.y * 64, n = blockIdx.z;
    const int tid = threadIdx.x;
    __shared__ u16 lds[64 * 72];   // [s_loc][c_loc], stride 72

    {
        int c_loc = tid & 63, s_seg = (tid >> 6) * 16;
        const float* src = x + ((size_t)n * 512 + c0 + c_loc) * 4096 + s0 + s_seg;
        for (int i4 = 0; i4 < 4; i4++) {
            float4 f = *(const float4*)(src + i4 * 4);
            int s = s_seg + i4 * 4;
            lds[(s + 0) * 72 + c_loc] = f2bf(f.x);
            lds[(s + 1) * 72 + c_loc] = f2bf(f.y);
            lds[(s + 2) * 72 + c_loc] = f2bf(f.z);
            lds[(s + 3) * 72 + c_loc] = f2bf(f.w);
        }
    }
    __syncthreads();
    {
        int s_loc = tid >> 2, c_seg = (tid & 3) * 16;
        u16* dst = Xt + ((size_t)n * 4096 + s0 + s_loc) * 512 + c0 + c_seg;
        *(us8*)(dst)     = *(const us8*)&lds[s_loc * 72 + c_seg];
        *(us8*)(dst + 8) = *(const us8*)&lds[s_loc * 72 + c_seg + 8];
    }
}

// ---------------------------------------------------------------------------
// Kernel 0b: weight convert. Wall_bf[384][512] = [theta;phi;g], Wo_bf[512][256].
// ---------------------------------------------------------------------------
__global__ __launch_bounds__(256) void wconv_kernel(
    const float* __restrict__ w_theta, const float* __restrict__ w_phi,
    const float* __restrict__ w_g, const float* __restrict__ w_o,
    u16* __restrict__ Wall_bf, u16* __restrict__ Wo_bf)
{
    int base = (blockIdx.x * 256 + threadIdx.x) * 4;   // 327680 total elems
    const float* src; u16* dst;
    if (base < 32768)       { src = w_theta + base;          dst = Wall_bf + base; }
    else if (base < 65536)  { src = w_phi + (base - 32768);  dst = Wall_bf + base; }
    else if (base < 196608) { src = w_g + (base - 65536);    dst = Wall_bf + base; }
    else                    { src = w_o + (base - 196608);   dst = Wo_bf + (base - 196608); }
    float4 f = *(const float4*)src;
    us4 v; v[0] = f2bf(f.x); v[1] = f2bf(f.y); v[2] = f2bf(f.z); v[3] = f2bf(f.w);
    *(us4*)dst = v;
}

// ---------------------------------------------------------------------------
// Kernel 1: projection GEMM (transposed output).
// PT[n][s][384] = Xt[n][s][:512] . Wall_bf[row][:512]^T
// ---------------------------------------------------------------------------
__global__ __launch_bounds__(256) void projT_gemm(
    const u16* __restrict__ Xt, const u16* __restrict__ Wall_bf,
    u16* __restrict__ PT)
{
    const int s0 = blockIdx.x * 128;     // 32 tiles
    const int r0 = blockIdx.y * 128;     // 3 tiles (384 rows)
    const int nb = blockIdx.z;
    const int tid = threadIdx.x;
    const int wave = tid >> 6, lane = tid & 63;
    const int quad = lane >> 4, l15 = lane & 15;
    const int wm = (wave >> 1) * 64, wn = (wave & 1) * 64;

    __shared__ u16 a_lds[128 * 40];   // [s_loc][k], stride 40
    __shared__ u16 b_lds[128 * 40];   // [row_loc][k], stride 40

    f4 acc[4][4];
    f4 z = {0.f, 0.f, 0.f, 0.f};
    for (int i = 0; i < 4; i++) for (int j = 0; j < 4; j++) acc[i][j] = z;

    const u16* Abase = Xt + ((size_t)nb * 4096 + s0) * 512;
    const int m = tid >> 1, kseg = (tid & 1) * 16;

    for (int k0 = 0; k0 < 512; k0 += 32) {
        *(us8*)&a_lds[m * 40 + kseg]     = *(const us8*)(Abase + (size_t)m * 512 + k0 + kseg);
        *(us8*)&a_lds[m * 40 + kseg + 8] = *(const us8*)(Abase + (size_t)m * 512 + k0 + kseg + 8);
        *(us8*)&b_lds[m * 40 + kseg]     = *(const us8*)(Wall_bf + (size_t)(r0 + m) * 512 + k0 + kseg);
        *(us8*)&b_lds[m * 40 + kseg + 8] = *(const us8*)(Wall_bf + (size_t)(r0 + m) * 512 + k0 + kseg + 8);
        __syncthreads();
        bf8 af[4], bfr[4];
        for (int i = 0; i < 4; i++)
            af[i]  = __builtin_bit_cast(bf8, *(const us8*)&a_lds[(wm + i*16 + l15)*40 + quad*8]);
        for (int j = 0; j < 4; j++)
            bfr[j] = __builtin_bit_cast(bf8, *(const us8*)&b_lds[(wn + j*16 + l15)*40 + quad*8]);
        for (int i = 0; i < 4; i++)
            for (int j = 0; j < 4; j++)
                acc[i][j] = mfma16(af[i], bfr[j], acc[i][j]);
        __syncthreads();
    }
    for (int i = 0; i < 4; i++) {
        int s_idx = s0 + wm + i * 16 + quad * 4;
        for (int rr = 0; rr < 4; rr++) {
            u16* dst = PT + ((size_t)nb * 4096 + s_idx + rr) * 384 + r0 + wn + l15;
            for (int j = 0; j < 4; j++)
                dst[j * 16] = f2bf(acc[i][j][rr]);
        }
    }
}

// ---------------------------------------------------------------------------
// Kernel 3: phi pool.  PT[n][s][64:128] --2x2 maxpool over s--> phiT[n][t][64]
// ---------------------------------------------------------------------------
__global__ __launch_bounds__(256) void phi_pool2(
    const u16* __restrict__ PT, u16* __restrict__ phiT)
{
    int n = blockIdx.y, t0 = blockIdx.x * 64;
    int tid = threadIdx.x;
    int t_loc = tid >> 2, d0 = (tid & 3) * 16;
    int t = t0 + t_loc;
    int h2 = t >> 5, w2 = t & 31;
    int s00 = h2 * 128 + w2 * 2;
    const u16* base = PT + ((size_t)n * 4096) * 384 + 64 + d0;
    us8 r[4][2];
    int soff[4] = {s00, s00 + 1, s00 + 64, s00 + 65};
    for (int p = 0; p < 4; p++) {
        r[p][0] = *(const us8*)(base + (size_t)soff[p] * 384);
        r[p][1] = *(const us8*)(base + (size_t)soff[p] * 384 + 8);
    }
    us8 o0, o1;
    for (int i = 0; i < 8; i++) {
        o0[i] = max4bf(r[0][0][i], r[1][0][i], r[2][0][i], r[3][0][i]);
        o1[i] = max4bf(r[0][1][i], r[1][1][i], r[2][1][i], r[3][1][i]);
    }
    u16* dst = phiT + ((size_t)n * 1024 + t) * 64 + d0;
    *(us8*)dst = o0;
    *(us8*)(dst + 8) = o1;
}

// ---------------------------------------------------------------------------
// Kernel 4: g pool + transpose. PT[n][s][128:384] --pool--> gP[n][256][1024]
// ---------------------------------------------------------------------------
__global__ __launch_bounds__(256) void g_poolT(
    const u16* __restrict__ PT, u16* __restrict__ gP)
{
    int t0 = blockIdx.x * 64, d0 = blockIdx.y * 64, n = blockIdx.z;
    int tid = threadIdx.x;
    __shared__ u16 lds[64 * 72];   // [d_loc][t_loc], stride 72

    {
        int t_loc = tid & 63, dseg = (tid >> 6) * 16;
        int t = t0 + t_loc;
        int h2 = t >> 5, w2 = t & 31;
        int s00 = h2 * 128 + w2 * 2;
        const u16* base = PT + ((size_t)n * 4096) * 384 + 128 + d0 + dseg;
        us8 r[4][2];
        int soff[4] = {s00, s00 + 1, s00 + 64, s00 + 65};
        for (int p = 0; p < 4; p++) {
            r[p][0] = *(const us8*)(base + (size_t)soff[p] * 384);
            r[p][1] = *(const us8*)(base + (size_t)soff[p] * 384 + 8);
        }
        for (int i = 0; i < 8; i++) {
            lds[(dseg + i) * 72 + t_loc]     = max4bf(r[0][0][i], r[1][0][i], r[2][0][i], r[3][0][i]);
            lds[(dseg + 8 + i) * 72 + t_loc] = max4bf(r[0][1][i], r[1][1][i], r[2][1][i], r[3][1][i]);
        }
    }
    __syncthreads();
    {
        int d_loc = tid >> 2, t_seg = (tid & 3) * 16;
        u16* dst = gP + ((size_t)n * 256 + d0 + d_loc) * 1024 + t0 + t_seg;
        *(us8*)(dst)     = *(const us8*)&lds[d_loc * 72 + t_seg];
        *(us8*)(dst + 8) = *(const us8*)&lds[d_loc * 72 + t_seg + 8];
    }
}

// ---------------------------------------------------------------------------
// Kernel 5: attention, restructured (round 3).
//  - S^T trick: QK computed as D[t][q] (A=phi, B=theta) so exp'd P packs into
//    us4 ds_write_b64 (conflict-free at stride 40); lsum is per-lane scalar.
//  - PV as D[d2][q] (A=G, B=P) -> epilogue packs us4 global stores.
//  - Register prefetch: chunk i+1's phi/g global loads issued before chunk i's
//    compute; regs -> LDS after barrier. Global latency hidden behind MFMA.
// Per block: 64 queries (16/wave), T-chunks of 32. Single pass, no
// max-subtract (|score| < ~14 -> exp safe in fp32).
// ---------------------------------------------------------------------------
__global__ __launch_bounds__(256) void attn_kernel(
    const u16* __restrict__ PT, const u16* __restrict__ phiT,
    const u16* __restrict__ gP, u16* __restrict__ yT)
{
    int n = blockIdx.y;
    int tid = threadIdx.x;
    int wave = tid >> 6, lane = tid & 63, quad = lane >> 4, l15 = lane & 15;
    int q0 = blockIdx.x * 64 + wave * 16;

    __shared__ u16 phi_lds[32 * 72];     // [t_loc][d], stride 72
    __shared__ u16 g_lds[256 * 40];      // [d2][t_loc], stride 40
    __shared__ u16 p_lds[4][16 * 40];    // per-wave [q_loc][t_loc], stride 40

    // theta fragments (B-operand: B[n=q][k=d]), strided view of PT cols [0:64)
    const u16* th = PT + ((size_t)n * 4096 + q0 + l15) * 384 + quad * 8;
    bf8 bth0 = __builtin_bit_cast(bf8, *(const us8*)(th));
    bf8 bth1 = __builtin_bit_cast(bf8, *(const us8*)(th + 32));

    // staging source addresses
    const int t_loc = tid >> 3, d0 = (tid & 7) * 8;
    const u16* phi_src = phiT + ((size_t)n * 1024 + t_loc) * 64 + d0;
    const u16* g_src   = gP + ((size_t)n * 256 + tid) * 1024;

    f4 z = {0.f, 0.f, 0.f, 0.f};
    f4 acc[16];
    for (int b = 0; b < 16; b++) acc[b] = z;
    float lsum = 0.f;

    // prologue: load chunk 0, store to LDS
    us8 pf_phi = *(const us8*)(phi_src);
    us8 pf_g0  = *(const us8*)(g_src + 0);
    us8 pf_g1  = *(const us8*)(g_src + 8);
    us8 pf_g2  = *(const us8*)(g_src + 16);
    us8 pf_g3  = *(const us8*)(g_src + 24);
    *(us8*)&phi_lds[t_loc * 72 + d0] = pf_phi;
    *(us8*)&g_lds[tid * 40 + 0]  = pf_g0;
    *(us8*)&g_lds[tid * 40 + 8]  = pf_g1;
    *(us8*)&g_lds[tid * 40 + 16] = pf_g2;
    *(us8*)&g_lds[tid * 40 + 24] = pf_g3;
    __syncthreads();

    for (int ci = 0; ci < 32; ci++) {
        // prefetch chunk ci+1 (clamped; last iter redundantly reloads ci=31)
        int nc = (ci + 1 < 32) ? (ci + 1) : ci;
        pf_phi = *(const us8*)(phi_src + (size_t)nc * 2048);
        pf_g0  = *(const us8*)(g_src + nc * 32 + 0);
        pf_g1  = *(const us8*)(g_src + nc * 32 + 8);
        pf_g2  = *(const us8*)(g_src + nc * 32 + 16);
        pf_g3  = *(const us8*)(g_src + nc * 32 + 24);

        // ---- compute chunk ci from LDS ----
        // S^T tiles: D[t=tt+quad*4+rr][q=l15]
        for (int tt = 0; tt < 32; tt += 16) {
            bf8 ap0 = __builtin_bit_cast(bf8, *(const us8*)&phi_lds[(tt + l15) * 72 + quad * 8]);
            bf8 ap1 = __builtin_bit_cast(bf8, *(const us8*)&phi_lds[(tt + l15) * 72 + 32 + quad * 8]);
            f4 s = mfma16(ap0, bth0, z);
            s = mfma16(ap1, bth1, s);
            us4 pk;
            float ps = 0.f;
            for (int rr = 0; rr < 4; rr++) {
                float p = __expf(s[rr]);
                ps += p;
                pk[rr] = f2bf(p);
            }
            lsum += ps;
            *(us4*)&p_lds[wave][l15 * 40 + tt + quad * 4] = pk;
        }
        // PV: A=G[m=d2][k=t], B=P[n=q][k=t] -> D[d2][q]
        bf8 bp = __builtin_bit_cast(bf8, *(const us8*)&p_lds[wave][l15 * 40 + quad * 8]);
        for (int b = 0; b < 16; b++) {
            bf8 ag = __builtin_bit_cast(bf8, *(const us8*)&g_lds[(b * 16 + l15) * 40 + quad * 8]);
            acc[b] = mfma16(ag, bp, acc[b]);
        }
        __syncthreads();
        // ---- stage prefetched chunk into LDS ----
        *(us8*)&phi_lds[t_loc * 72 + d0] = pf_phi;
        *(us8*)&g_lds[tid * 40 + 0]  = pf_g0;
        *(us8*)&g_lds[tid * 40 + 8]  = pf_g1;
        *(us8*)&g_lds[tid * 40 + 16] = pf_g2;
        *(us8*)&g_lds[tid * 40 + 24] = pf_g3;
        __syncthreads();
    }

    // softmax denominator: per-lane sum for q=l15; reduce across the 4 quads
    float v = lsum;
    v += __shfl_xor(v, 16);
    v += __shfl_xor(v, 32);
    float inv = 1.0f / v;

    // epilogue: acc[b][rr] = O[d2 = b*16+quad*4+rr][q = l15]
    u16* dst = yT + ((size_t)n * 4096 + q0 + l15) * 256 + quad * 4;
    for (int b = 0; b < 16; b++) {
        us4 o;
        for (int rr = 0; rr < 4; rr++) o[rr] = f2bf(acc[b][rr] * inv);
        *(us4*)(dst + b * 16) = o;
    }
}

// ---------------------------------------------------------------------------
// Kernel 6: o-projection + residual (pre-converted bf16 W_o).
// out[n][c][s] = gamma * (Wo_bf[c][:] . yT[n][s][:]) + x[n][c][s]
// ---------------------------------------------------------------------------
__global__ __launch_bounds__(256) void oproj_gemm(
    const u16* __restrict__ Wo_bf, const u16* __restrict__ yT,
    const float* __restrict__ x, const float* __restrict__ gamma,
    float* __restrict__ out)
{
    const int nt = blockIdx.x;          // 0..31 (s tiles)
    const int mt = blockIdx.y;          // 0..7  (c tiles)
    const int nb = blockIdx.z;
    const int tid = threadIdx.x;
    const int wave = tid >> 6, lane = tid & 63;
    const int quad = lane >> 4, l15 = lane & 15;
    const int wm = (wave >> 1) * 32, wn = (wave & 1) * 64;
    const int s0 = nt * 128;

    __shared__ u16 a_lds[64 * 40];
    __shared__ u16 b_lds[128 * 40];

    f4 acc[2][4];
    f4 z = {0.f, 0.f, 0.f, 0.f};
    for (int i = 0; i < 2; i++) for (int j = 0; j < 4; j++) acc[i][j] = z;

    for (int k0 = 0; k0 < 256; k0 += 32) {
        {
            int m = tid >> 2, kq = (tid & 3) * 8;
            *(us8*)&a_lds[m * 40 + kq] =
                *(const us8*)(Wo_bf + (size_t)(mt * 64 + m) * 256 + k0 + kq);
        }
        {
            int s_loc = tid >> 1, kq = (tid & 1) * 16;
            const u16* src = yT + ((size_t)nb * 4096 + s0 + s_loc) * 256 + k0 + kq;
            *(us8*)&b_lds[s_loc * 40 + kq]     = *(const us8*)(src);
            *(us8*)&b_lds[s_loc * 40 + kq + 8] = *(const us8*)(src + 8);
        }
        __syncthreads();
        bf8 af[2], bfr[4];
        for (int i = 0; i < 2; i++)
            af[i] = __builtin_bit_cast(bf8, *(const us8*)&a_lds[(wm + i*16 + l15)*40 + quad*8]);
        for (int j = 0; j < 4; j++)
            bfr[j] = __builtin_bit_cast(bf8, *(const us8*)&b_lds[(wn + j*16 + l15)*40 + quad*8]);
        for (int i = 0; i < 2; i++)
            for (int j = 0; j < 4; j++)
                acc[i][j] = mfma16(af[i], bfr[j], acc[i][j]);
        __syncthreads();
    }
    float g0 = gamma[0];
    for (int i = 0; i < 2; i++) {
        int c = mt * 64 + wm + i * 16 + quad * 4;
        for (int j = 0; j < 4; j++) {
            int s = s0 + wn + j * 16 + l15;
            for (int rr = 0; rr < 4; rr++) {
                size_t idx = ((size_t)nb * 512 + c + rr) * 4096 + s;
                out[idx] = g0 * acc[i][j][rr] + x[idx];
            }
        }
    }
}

// ---------------------------------------------------------------------------
// Workspace layout (bytes). Xt region is dead after projT_gemm, so yT/phiT/gP
// overlay it. Total = 118,095,872 B (~113 MB).
// ---------------------------------------------------------------------------
extern "C" void kernel_launch(void* const* d_in, const int* in_sizes, int n_in,
                              void* d_out, int out_size, void* d_ws, size_t ws_size,
                              hipStream_t stream)
{
    (void)in_sizes; (void)n_in; (void)out_size; (void)ws_size;
    const float* x       = (const float*)d_in[0];
    const float* w_theta = (const float*)d_in[1];
    const float* w_phi   = (const float*)d_in[2];
    const float* w_g     = (const float*)d_in[3];
    const float* w_o     = (const float*)d_in[4];
    const float* gamma   = (const float*)d_in[5];
    float* out = (float*)d_out;

    char* ws = (char*)d_ws;
    u16* Xt      = (u16*)(ws);
    u16* yT      = (u16*)(ws);                 // overlays Xt (dead by then)
    u16* phiT    = (u16*)(ws + 33554432);      // overlays Xt
    u16* gP      = (u16*)(ws + 35651584);      // overlays Xt
    u16* Wall_bf = (u16*)(ws + 67108864);
    u16* Wo_bf   = (u16*)(ws + 67502080);
    u16* PT      = (u16*)(ws + 67764224);

    xt_kernel  <<<dim3(64, 8, 16), 256, 0, stream>>>(x, Xt);
    wconv_kernel<<<320, 256, 0, stream>>>(w_theta, w_phi, w_g, w_o, Wall_bf, Wo_bf);
    projT_gemm <<<dim3(32, 3, 16), 256, 0, stream>>>(Xt, Wall_bf, PT);
    phi_pool2  <<<dim3(16, 16),    256, 0, stream>>>(PT, phiT);
    g_poolT    <<<dim3(16, 4, 16), 256, 0, stream>>>(PT, gP);
    attn_kernel<<<dim3(64, 16),    256, 0, stream>>>(PT, phiT, gP, yT);
    oproj_gemm <<<dim3(32, 8, 16), 256, 0, stream>>>(Wo_bf, yT, x, gamma, out);
}